// Round 3
// baseline (848.517 us; speedup 1.0000x reference)
//
#include <hip/hip_runtime.h>

typedef __attribute__((ext_vector_type(8))) short bf8v;  // 8 bf16 = 4 VGPRs (MFMA A/B frag)
typedef __attribute__((ext_vector_type(4))) float f4v;   // MFMA C/D frag

#define BB 8
#define CC 3
#define HH 512
#define WW 512
#define OO 64
#define KK 9
#define HW (HH * WW)
#define VBSTRIDE 176  // bytes per pixel row in LDS staging (hi@0, lo@64, pad->2-way banks)

static __device__ __forceinline__ unsigned short f2bf(float f) {
    unsigned u = __builtin_bit_cast(unsigned, f);
    unsigned r = u + 0x7fffu + ((u >> 16) & 1u);   // RNE
    return (unsigned short)(r >> 16);
}
static __device__ __forceinline__ float bf2f(unsigned short h) {
    unsigned u = ((unsigned)h) << 16;
    return __builtin_bit_cast(float, u);
}

__global__ __launch_bounds__(256, 3) void fused_deform_kernel(
    const float* __restrict__ x,
    const float* __restrict__ w_simple,
    const float* __restrict__ w_off,
    const float* __restrict__ b_off,
    const float* __restrict__ w_mask,
    const float* __restrict__ b_mask,
    float* __restrict__ out)
{
    // Conv weights in LDS (broadcast reads); einsum weights live in registers as
    // bf16 hi/lo MFMA fragments. Per-wave V staging tile for the MFMA einsum.
    __shared__ __align__(16) float s_woff[18 * 28];
    __shared__ __align__(16) float s_wmsk[9 * 28];
    __shared__ float s_boff[18];
    __shared__ float s_bmsk[9];
    __shared__ __align__(16) unsigned char s_vb[4 * 64 * VBSTRIDE];  // 45 KB

    const int tid = threadIdx.x;
    const int lane = tid & 63;
    const int wv = tid >> 6;

    for (int t = tid; t < 18 * 28; t += 256) { int j = t / 28, i = t % 28; s_woff[t] = (i < 27) ? w_off[j * 27 + i] : 0.f; }
    for (int t = tid; t < 9 * 28; t += 256)  { int j = t / 28, i = t % 28; s_wmsk[t] = (i < 27) ? w_mask[j * 27 + i] : 0.f; }
    if (tid < 18) s_boff[tid] = b_off[tid];
    if (tid < 9)  s_bmsk[tid] = b_mask[tid];

    // ---- einsum W -> MFMA A-fragments (bf16 hi/lo split), 4 o-tiles of 16 ----
    // A layout (16x16x32): lane holds A[row = lane&15][k = (lane>>4)*8 + j], j=0..7.
    bf8v wh[4], wl[4];
    {
        const int row = lane & 15;
        const int ko = (lane >> 4) * 8;
        #pragma unroll
        for (int m = 0; m < 4; ++m) {
            const float* ws = w_simple + (size_t)(m * 16 + row) * 27 + ko;
            #pragma unroll
            for (int j = 0; j < 8; ++j) {
                float f = (ko + j < 27) ? ws[j] : 0.f;
                unsigned short hh = f2bf(f);
                unsigned short ll = f2bf(f - bf2f(hh));
                wh[m][j] = (short)hh;
                wl[m][j] = (short)ll;
            }
        }
    }
    __syncthreads();

    // XCD swizzle: 8192 blocks; XCD i owns blocks [i*1024,(i+1)*1024) = batch image i.
    const int bid = blockIdx.x;
    const int nbid = (bid & 7) * 1024 + (bid >> 3);

    const int idx = nbid * 256 + tid;
    const int w = idx & (WW - 1);
    const int h = (idx >> 9) & (HH - 1);
    const int b = idx >> 18;

    const float* xb = x + (size_t)b * CC * HW;

    // ---- 3x3 neighborhood (zero-padded) ----
    float nb[28];
    #pragma unroll
    for (int c = 0; c < CC; ++c) {
        const float* xc = xb + c * HW;
        #pragma unroll
        for (int i = 0; i < 9; ++i) {
            int yy = h - 1 + i / 3;
            int xx = w - 1 + i % 3;
            float v = 0.f;
            if ((unsigned)yy < (unsigned)HH && (unsigned)xx < (unsigned)WW)
                v = xc[yy * WW + xx];
            nb[c * 9 + i] = v;
        }
    }
    nb[27] = 0.f;

    // ---- offset conv (18 ch) ----
    float offv[18];
    #pragma unroll
    for (int j = 0; j < 18; ++j) {
        float acc = s_boff[j];
        const float4* wp = (const float4*)(s_woff + j * 28);
        #pragma unroll
        for (int q = 0; q < 7; ++q) {
            float4 wq = wp[q];
            acc = fmaf(wq.x, nb[q * 4 + 0], acc);
            acc = fmaf(wq.y, nb[q * 4 + 1], acc);
            acc = fmaf(wq.z, nb[q * 4 + 2], acc);
            acc = fmaf(wq.w, nb[q * 4 + 3], acc);
        }
        offv[j] = acc;
    }

    // ---- mask conv (9 ch) + sigmoid ----
    float mval[9];
    #pragma unroll
    for (int j = 0; j < 9; ++j) {
        float acc = s_bmsk[j];
        const float4* wp = (const float4*)(s_wmsk + j * 28);
        #pragma unroll
        for (int q = 0; q < 7; ++q) {
            float4 wq = wp[q];
            acc = fmaf(wq.x, nb[q * 4 + 0], acc);
            acc = fmaf(wq.y, nb[q * 4 + 1], acc);
            acc = fmaf(wq.z, nb[q * 4 + 2], acc);
            acc = fmaf(wq.w, nb[q * 4 + 3], acc);
        }
        mval[j] = __builtin_amdgcn_rcpf(1.f + __expf(-acc));
    }

    // ---- deformable bilinear sampling (branchless) ----
    float vv[27];
    #pragma unroll
    for (int k = 0; k < 9; ++k) {
        float py = (float)(h - 1 + k / 3) + offv[2 * k + 0];
        float px = (float)(w - 1 + k % 3) + offv[2 * k + 1];
        float y0f = floorf(py);
        float x0f = floorf(px);
        float ty = py - y0f;
        float tx = px - x0f;
        int y0 = (int)y0f;
        int x0 = (int)x0f;
        int y1 = y0 + 1;
        int x1 = x0 + 1;
        bool vy0 = (unsigned)y0 < (unsigned)HH;
        bool vy1 = (unsigned)y1 < (unsigned)HH;
        bool vx0 = (unsigned)x0 < (unsigned)WW;
        bool vx1 = (unsigned)x1 < (unsigned)WW;
        int yc0 = min(max(y0, 0), HH - 1);
        int yc1 = min(max(y1, 0), HH - 1);
        int xc0 = min(max(x0, 0), WW - 1);
        int xc1 = min(max(x1, 0), WW - 1);
        int l00 = yc0 * WW + xc0;
        int l01 = yc0 * WW + xc1;
        int l10 = yc1 * WW + xc0;
        int l11 = yc1 * WW + xc1;
        float mk = mval[k];
        float w00 = (vy0 && vx0) ? (1.f - ty) * (1.f - tx) * mk : 0.f;
        float w01 = (vy0 && vx1) ? (1.f - ty) * tx * mk : 0.f;
        float w10 = (vy1 && vx0) ? ty * (1.f - tx) * mk : 0.f;
        float w11 = (vy1 && vx1) ? ty * tx * mk : 0.f;
        #pragma unroll
        for (int c = 0; c < CC; ++c) {
            const float* xc = xb + c * HW;
            float s;
            s = w00 * xc[l00];
            s = fmaf(w01, xc[l01], s);
            s = fmaf(w10, xc[l10], s);
            s = fmaf(w11, xc[l11], s);
            vv[c * 9 + k] = s;
        }
    }

    // ---- stage vv into per-wave LDS tile as bf16 hi/lo (pad 27->32 with 0) ----
    unsigned char* vb = s_vb + wv * (64 * VBSTRIDE);
    {
        unsigned hiw[16], low[16];
        #pragma unroll
        for (int i = 0; i < 16; ++i) {
            float a = (2 * i < 27) ? vv[2 * i] : 0.f;
            float c2 = (2 * i + 1 < 27) ? vv[2 * i + 1] : 0.f;
            unsigned short ha = f2bf(a), hb = f2bf(c2);
            unsigned short la = f2bf(a - bf2f(ha)), lb = f2bf(c2 - bf2f(hb));
            hiw[i] = (unsigned)ha | ((unsigned)hb << 16);
            low[i] = (unsigned)la | ((unsigned)lb << 16);
        }
        uint4* dh = (uint4*)(vb + lane * VBSTRIDE);
        dh[0] = make_uint4(hiw[0], hiw[1], hiw[2], hiw[3]);
        dh[1] = make_uint4(hiw[4], hiw[5], hiw[6], hiw[7]);
        dh[2] = make_uint4(hiw[8], hiw[9], hiw[10], hiw[11]);
        dh[3] = make_uint4(hiw[12], hiw[13], hiw[14], hiw[15]);
        uint4* dl = (uint4*)(vb + lane * VBSTRIDE + 64);
        dl[0] = make_uint4(low[0], low[1], low[2], low[3]);
        dl[1] = make_uint4(low[4], low[5], low[6], low[7]);
        dl[2] = make_uint4(low[8], low[9], low[10], low[11]);
        dl[3] = make_uint4(low[12], low[13], low[14], low[15]);
    }
    // Same-wave producer/consumer: drain LDS writes, block reordering.
    asm volatile("s_waitcnt lgkmcnt(0)" ::: "memory");

    // ---- MFMA einsum: out[o, px] = W[o, ck] * V[ck, px], bf16x2 split ----
    // B layout: lane holds B[k=(lane>>4)*8+j][col=lane&15]; col g*16+(lane&15).
    // D layout (m89): o = m*16 + (lane>>4)*4 + r, col = lane&15.
    const int wavecol = ((nbid & 1) << 8) + wv * 64;
    const int kb16 = (lane >> 4) * 16;      // byte offset of this lane's k-block
    float* obase = out + (size_t)b * OO * HW + (size_t)h * WW;
    #pragma unroll
    for (int g = 0; g < 4; ++g) {
        const unsigned char* rs = vb + (size_t)(g * 16 + (lane & 15)) * VBSTRIDE + kb16;
        bf8v bh = *(const bf8v*)rs;
        bf8v bl = *(const bf8v*)(rs + 64);
        float* op0 = obase + (wavecol + g * 16 + (lane & 15));
        #pragma unroll
        for (int m = 0; m < 4; ++m) {
            f4v acc = {0.f, 0.f, 0.f, 0.f};
            acc = __builtin_amdgcn_mfma_f32_16x16x32_bf16(wh[m], bl, acc, 0, 0, 0);
            acc = __builtin_amdgcn_mfma_f32_16x16x32_bf16(wl[m], bh, acc, 0, 0, 0);
            acc = __builtin_amdgcn_mfma_f32_16x16x32_bf16(wh[m], bh, acc, 0, 0, 0);
            const int o0 = m * 16 + (lane >> 4) * 4;
            #pragma unroll
            for (int r = 0; r < 4; ++r)
                __builtin_nontemporal_store(acc[r], op0 + (size_t)(o0 + r) * HW);
        }
    }
}

extern "C" void kernel_launch(void* const* d_in, const int* in_sizes, int n_in,
                              void* d_out, int out_size, void* d_ws, size_t ws_size,
                              hipStream_t stream) {
    const float* x        = (const float*)d_in[0];
    const float* w_simple = (const float*)d_in[1];
    const float* w_off    = (const float*)d_in[2];
    const float* b_off    = (const float*)d_in[3];
    const float* w_mask   = (const float*)d_in[4];
    const float* b_mask   = (const float*)d_in[5];
    float* out = (float*)d_out;

    const int total = BB * HH * WW;           // 2,097,152 pixels
    const int block = 256;
    const int grid = total / block;           // 8192 blocks
    fused_deform_kernel<<<grid, block, 0, stream>>>(x, w_simple, w_off, b_off, w_mask, b_mask, out);
}